// Round 20
// baseline (348.592 us; speedup 1.0000x reference)
//
#include <hip/hip_runtime.h>
#include <hip/hip_bf16.h>
#include <cstdint>

typedef unsigned short u16;
typedef unsigned int u32;
typedef short s16x8 __attribute__((ext_vector_type(8)));
typedef float f32x4 __attribute__((ext_vector_type(4)));

// Problem constants (B=4, T=2048, D=1024, E=8, H=2048, K=2)
constexpr int NTOK = 8192;
constexpr int DDIM = 1024;
constexpr int NEXP = 8;
constexpr int HDIM = 2048;
constexpr int NPAIR = NTOK * 2;   // 16384

// d_out layout (floats), concatenated tuple
constexpr size_t OFF_OUT   = 0;
constexpr size_t OFF_AUX   = 8388608;
constexpr size_t OFF_PROBS = 8388609;
constexpr size_t OFF_TIDX  = 8454145;
constexpr size_t OFF_TPR   = 8470529;

// workspace layout (bytes)
constexpr size_t WS_CNT  = 0;          // 8 int
constexpr size_t WS_PSUM = 32;         // 8 float
constexpr size_t WS_IDS  = 1024;       // 8*8192 int   -> ends 263168
constexpr size_t WS_PRW  = 263168;     // 8*8192 float -> ends 525312
constexpr size_t WS_W1T  = 17302528;   // 8*2048*1024 bf16 (transposed [E][H][D])
constexpr size_t WS_W2T  = 50856960;   // 8*1024*2048 bf16 (transposed [E][D][H])
constexpr size_t WS_H    = 84411392;   // 16384*2048 bf16
constexpr size_t WS_XB   = 151520256;  // 8192*1024 bf16 (x converted, token order)
constexpr size_t WS_NEED = 168297472;

__device__ __forceinline__ u16 f2b(float f) {
  u32 u = __float_as_uint(f);
  u32 r = (u + 0x7fffu + ((u >> 16) & 1u)) >> 16;
  return (u16)r;
}

typedef const uint32_t __attribute__((address_space(1)))* gptr_t;
typedef uint32_t __attribute__((address_space(3)))* lptr_t;

__device__ __forceinline__ void gload16(const void* gp, void* lp) {
  __builtin_amdgcn_global_load_lds((gptr_t)gp, (lptr_t)(uintptr_t)lp, 16, 0, 0);
}

// ======== PREP: router (0..127) + w1 transpose (128..4223) + out-zeroing (4224..4735) ========
__global__ __launch_bounds__(256) void prep_kernel(
    const float* __restrict__ x, const float* __restrict__ gw,
    float* __restrict__ outbuf,
    int* __restrict__ cnt, float* __restrict__ psum,
    int* __restrict__ ids, float* __restrict__ prw, u16* __restrict__ xb,
    const float* __restrict__ w1, u16* __restrict__ w1t) {
  __shared__ float smem[DDIM * NEXP];  // 32 KB: router gate staging / tconv tile
  __shared__ int lcnt[NEXP];
  __shared__ float psl[NEXP];
  __shared__ int gbl[NEXP];

  const int bid = blockIdx.x;
  const int tid = threadIdx.x;

  if (bid >= 4224) {
    // ---------------- out-zeroing role (32 MB over 512 blocks) ----------------
    float4 z = {0.f, 0.f, 0.f, 0.f};
    float4* dst = (float4*)(outbuf + OFF_OUT) + (size_t)(bid - 4224) * 4096 + tid;
#pragma unroll
    for (int i = 0; i < 16; ++i) dst[i * 256] = z;
    return;
  }

  if (bid >= 128) {
    // ---------------- w1 tconv role: [E][1024][2048] -> [E][2048][1024] ----------------
    int id = bid - 128;
    int e = id >> 9, r = id & 511;
    int c0 = (r & 31) * 64, r0 = (r >> 5) * 64;

    float (*tile)[65] = (float(*)[65])smem;
    int tx = tid & 15, ty = tid >> 4;
    const float* src = w1 + (size_t)e * DDIM * HDIM;
#pragma unroll
    for (int i = 0; i < 4; ++i) {
      int rr = ty + i * 16;
      float4 v = *(const float4*)(src + (size_t)(r0 + rr) * HDIM + c0 + tx * 4);
      tile[rr][tx * 4 + 0] = v.x; tile[rr][tx * 4 + 1] = v.y;
      tile[rr][tx * 4 + 2] = v.z; tile[rr][tx * 4 + 3] = v.w;
    }
    __syncthreads();
    u16* dst = w1t + (size_t)e * DDIM * HDIM;
#pragma unroll
    for (int i = 0; i < 4; ++i) {
      int c = ty + i * 16;
      ushort4 o;
      o.x = f2b(tile[tx * 4 + 0][c]); o.y = f2b(tile[tx * 4 + 1][c]);
      o.z = f2b(tile[tx * 4 + 2][c]); o.w = f2b(tile[tx * 4 + 3][c]);
      *(ushort4*)(dst + (size_t)(c0 + c) * DDIM + r0 + tx * 4) = o;
    }
    return;
  }

  // ---------------- router role (also emits xb = bf16(x)) ----------------
#pragma unroll
  for (int k = 0; k < 8; ++k)
    ((float4*)smem)[tid + k * 256] = ((const float4*)gw)[tid + k * 256];
  if (tid < NEXP) { lcnt[tid] = 0; psl[tid] = 0.f; }
  __syncthreads();

  const int tloc = tid >> 2, part = tid & 3;
  const int t = bid * 64 + tloc;
  double acc[NEXP];
#pragma unroll
  for (int e = 0; e < NEXP; ++e) acc[e] = 0.0;

  const float* xrow = x + (size_t)t * DDIM + part * 256;
  u16* xbrow = xb + (size_t)t * DDIM + part * 256;
  for (int i = 0; i < 64; ++i) {
    float4 v = ((const float4*)xrow)[i];
    ushort4 o;
    o.x = f2b(v.x); o.y = f2b(v.y); o.z = f2b(v.z); o.w = f2b(v.w);
    ((ushort4*)xbrow)[i] = o;
    const float* g = &smem[(part * 256 + i * 4) * NEXP];
#pragma unroll
    for (int j = 0; j < 4; ++j) {
      double xs = (double)((const float*)&v)[j];
#pragma unroll
      for (int e = 0; e < NEXP; ++e) acc[e] += xs * (double)g[j * NEXP + e];
    }
  }
#pragma unroll
  for (int e = 0; e < NEXP; ++e) {
    acc[e] += __shfl_xor(acc[e], 1);
    acc[e] += __shfl_xor(acc[e], 2);
  }

  int e0 = 0, e1 = 0, lp0 = 0, lp1 = 0;
  float tp0 = 0.f, tp1 = 0.f;
  if (part == 0) {
    float l[NEXP];
#pragma unroll
    for (int e = 0; e < NEXP; ++e) l[e] = (float)acc[e];
    float m = l[0];
#pragma unroll
    for (int e = 1; e < NEXP; ++e) m = fmaxf(m, l[e]);
    float p[NEXP], s = 0.f;
#pragma unroll
    for (int e = 0; e < NEXP; ++e) { p[e] = expf(l[e] - m); s += p[e]; }
    float inv = 1.0f / s;
#pragma unroll
    for (int e = 0; e < NEXP; ++e) {
      p[e] *= inv;
      outbuf[OFF_PROBS + (size_t)t * NEXP + e] = p[e];
      atomicAdd(&psl[e], p[e]);
    }
#pragma unroll
    for (int e = 1; e < NEXP; ++e) if (p[e] > p[e0]) e0 = e;
    e1 = -1;
#pragma unroll
    for (int e = 0; e < NEXP; ++e)
      if (e != e0 && (e1 < 0 || p[e] > p[e1])) e1 = e;
    float ps = p[e0] + p[e1];
    tp0 = p[e0] / ps;
    tp1 = p[e1] / ps;
    outbuf[OFF_TIDX + t * 2 + 0] = (float)e0;
    outbuf[OFF_TIDX + t * 2 + 1] = (float)e1;
    outbuf[OFF_TPR + t * 2 + 0] = tp0;
    outbuf[OFF_TPR + t * 2 + 1] = tp1;
    lp0 = atomicAdd(&lcnt[e0], 1);
    lp1 = atomicAdd(&lcnt[e1], 1);
  }
  __syncthreads();
  if (tid < NEXP) {
    gbl[tid] = atomicAdd(&cnt[tid], lcnt[tid]);
    atomicAdd(&psum[tid], psl[tid]);
  }
  __syncthreads();
  if (part == 0) {
    int pos0 = gbl[e0] + lp0;
    int pos1 = gbl[e1] + lp1;
    ids[e0 * NTOK + pos0] = t;
    ids[e1 * NTOK + pos1] = t;
    prw[e0 * NTOK + pos0] = tp0;
    prw[e1 * NTOK + pos1] = tp1;
  }
}

// -------- grouped GEMM: 128x128, BK=32, 3-ring one-barrier, supertile (R13-proven) --------
// MODE 0 grid = 12288: every 3rd block (r3==2) transposes one w2 tile; GEMM blocks use
// gid = g3*2+r3 (0..8191). MODE 1 grid = 8192 with SPLIT-K=2: ko = (gid>>3)&1 selects
// the K-half; epilogue is atomicAdd so partial sums are correctness-free. Both k-halves
// of a tile are gid-adjacent -> share A rows + B panel in L2.
// Ring: vmcnt(4) -> barrier -> STAGE(kt+2) -> compute(kt). XCD-affinity e = gid&7.
template <int MODE>
__global__ __launch_bounds__(256, 3) void moe_gemm_kernel(
    const u16* __restrict__ Asrc, const u16* __restrict__ Bt,
    u16* __restrict__ hout, float* __restrict__ yout,
    const int* __restrict__ cnt, const float* __restrict__ psum,
    const int* __restrict__ ids, const float* __restrict__ prw,
    float* __restrict__ outbuf,
    const float* __restrict__ w2, u16* __restrict__ w2t) {
  constexpr int KDIM = (MODE == 0) ? 1024 : 2048;
  constexpr int NDIM = (MODE == 0) ? 2048 : 1024;
  constexpr int KSPLIT = (MODE == 0) ? 1 : 2;
  constexpr int NT = KDIM / 32 / KSPLIT;   // K-steps per block
  constexpr int NB = NDIM / 128;   // n-blocks per expert
  constexpr int MGRP = 4;          // m-blocks per L2 supertile group
  constexpr int QPG = MGRP * NB;   // q's per group

  __shared__ u16 Al[3][128 * 32];  // 24 KB
  __shared__ u16 Bl[3][128 * 32];  // 24 KB

  const int wgid = blockIdx.x;
  const int tid = threadIdx.x;
  int gid;
  if (MODE == 0) {
    int g3 = wgid / 3, r3 = wgid - g3 * 3;
    if (r3 == 2) {
      // ---------------- w2 tconv role: [E][2048][1024] -> [E][1024][2048] ----------------
      int e = g3 >> 9, r = g3 & 511;
      int c0 = (r & 15) * 64, r0 = (r >> 4) * 64;
      float (*tile)[65] = (float(*)[65])Al;  // overlay on GEMM LDS (16.6 KB < 48 KB)
      int tx = tid & 15, ty = tid >> 4;
      const float* src = w2 + (size_t)e * HDIM * DDIM;
#pragma unroll
      for (int i = 0; i < 4; ++i) {
        int rr = ty + i * 16;
        float4 v = *(const float4*)(src + (size_t)(r0 + rr) * DDIM + c0 + tx * 4);
        tile[rr][tx * 4 + 0] = v.x; tile[rr][tx * 4 + 1] = v.y;
        tile[rr][tx * 4 + 2] = v.z; tile[rr][tx * 4 + 3] = v.w;
      }
      __syncthreads();
      u16* dst = w2t + (size_t)e * HDIM * DDIM;
#pragma unroll
      for (int i = 0; i < 4; ++i) {
        int c = ty + i * 16;
        ushort4 o;
        o.x = f2b(tile[tx * 4 + 0][c]); o.y = f2b(tile[tx * 4 + 1][c]);
        o.z = f2b(tile[tx * 4 + 2][c]); o.w = f2b(tile[tx * 4 + 3][c]);
        *(ushort4*)(dst + (size_t)(c0 + c) * HDIM + r0 + tx * 4) = o;
      }
      return;
    }
    gid = g3 * 2 + r3;
  } else {
    gid = wgid;
  }

  const int e = gid & 7;           // expert -> XCD lane
  int q = gid >> 3;
  int ko = 0;
  if (MODE == 1) { ko = q & 1; q >>= 1; }
  const int mg = q / QPG;
  const int r = q % QPG;
  const int m0 = (mg * MGRP + (r % MGRP)) * 128;
  const int n0 = (r / MGRP) * 128;

  int cn[NEXP];
#pragma unroll
  for (int i = 0; i < NEXP; ++i) cn[i] = cnt[i];
  const int cnte = cn[e];

  if (MODE == 0 && gid == 0 && tid == 0) {
    float aux = 0.f;
#pragma unroll
    for (int i = 0; i < NEXP; ++i) aux += (float)cn[i] * psum[i];
    outbuf[OFF_AUX] = aux * (float)NEXP / ((float)NTOK * (float)NTOK);
  }

  if (m0 >= cnte) return;
  int gbase = 0;
#pragma unroll
  for (int i = 0; i < NEXP; ++i) if (i < e) gbase += cn[i];

  const int lane = tid & 63, wid = tid >> 6;
  const int wm = (wid >> 1) * 64, wn = (wid & 1) * 64;
  const int r15 = lane & 15, l4 = lane >> 4;

  // staging precompute: per qq, LDS slot j=qq*256+tid -> row=j>>2, chunk cp=j&3,
  // holds global chunk c = cp ^ ((row>>1)&3)  (both-sides XOR swizzle)
  const char* aptr[2];
  const char* bptr[2];
  const size_t koff = (size_t)ko * NT * 64;  // byte offset of this block's K-half
#pragma unroll
  for (int qq = 0; qq < 2; ++qq) {
    int j = qq * 256 + tid;
    int row = j >> 2;
    int c = (j & 3) ^ ((row >> 1) & 3);
    size_t rowoff;
    if (MODE == 0) {
      int mm = m0 + row;
      if (mm > cnte - 1) mm = cnte - 1;
      int tok = ids[e * NTOK + mm];          // in-GEMM gather
      rowoff = (size_t)tok * KDIM;
    } else {
      int gr = gbase + m0 + row;
      if (gr > NPAIR - 1) gr = NPAIR - 1;
      rowoff = (size_t)gr * KDIM;
    }
    aptr[qq] = (const char*)Asrc + (rowoff + (size_t)c * 8) * 2 + koff;
    size_t nrow = (size_t)e * NDIM + n0 + row;
    bptr[qq] = (const char*)Bt + (nrow * KDIM + (size_t)c * 8) * 2 + koff;
  }

  f32x4 acc[4][4];
#pragma unroll
  for (int i = 0; i < 4; ++i)
#pragma unroll
    for (int jn = 0; jn < 4; ++jn) acc[i][jn] = (f32x4){0.f, 0.f, 0.f, 0.f};

#define STAGE(b_, kt_)                                                         \
  do {                                                                         \
    const size_t kofs_ = (size_t)(kt_) * 64;  /* bytes: 32 bf16 */             \
    _Pragma("unroll") for (int qq = 0; qq < 2; ++qq) {                         \
      gload16(aptr[qq] + kofs_, (void*)&Al[b_][(size_t)(qq * 256 + tid) * 8]); \
      gload16(bptr[qq] + kofs_, (void*)&Bl[b_][(size_t)(qq * 256 + tid) * 8]); \
    }                                                                          \
  } while (0)

  auto compute = [&](int b) {
    const s16x8* Av = (const s16x8*)Al[b];
    const s16x8* Bv = (const s16x8*)Bl[b];
    s16x8 af[4], bfr[4];
#pragma unroll
    for (int mi = 0; mi < 4; ++mi) {
      int row = wm + mi * 16 + r15;
      af[mi] = Av[row * 4 + (l4 ^ ((row >> 1) & 3))];
    }
#pragma unroll
    for (int ni = 0; ni < 4; ++ni) {
      int row = wn + ni * 16 + r15;
      bfr[ni] = Bv[row * 4 + (l4 ^ ((row >> 1) & 3))];
    }
#pragma unroll
    for (int mi = 0; mi < 4; ++mi)
#pragma unroll
      for (int ni = 0; ni < 4; ++ni)
        acc[mi][ni] = __builtin_amdgcn_mfma_f32_16x16x32_bf16(
            af[mi], bfr[ni], acc[mi][ni], 0, 0, 0);
  };

  // prologue: tiles 0,1 staged into bufs 0,1 (8 loads/thread outstanding)
  STAGE(0, 0);
  STAGE(1, 1);

  int b0 = 0;
  for (int kt = 0; kt < NT; ++kt) {
    if (kt < NT - 1)
      asm volatile("s_waitcnt vmcnt(4)" ::: "memory");  // tile kt landed, kt+1 in flight
    else
      asm volatile("s_waitcnt vmcnt(0)" ::: "memory");  // last tile: drain
    __builtin_amdgcn_s_barrier();  // all waves: tile kt ready AND compute(kt-1) done
    asm volatile("" ::: "memory");
    if (kt + 2 < NT) {
      int bs = b0 + 2; if (bs >= 3) bs -= 3;
      STAGE(bs, kt + 2);  // into buffer freed by compute(kt-1)
    }
    compute(b0);
    if (++b0 == 3) b0 = 0;
  }
#undef STAGE

  // epilogue: C/D layout col = lane&15, row = (lane>>4)*4 + j
#pragma unroll
  for (int mi = 0; mi < 4; ++mi) {
#pragma unroll
    for (int jr = 0; jr < 4; ++jr) {
      int rl = wm + mi * 16 + l4 * 4 + jr;
      if (m0 + rl < cnte) {
        if (MODE == 0) {
          size_t grow = (size_t)(gbase + m0 + rl);
#pragma unroll
          for (int ni = 0; ni < 4; ++ni) {
            float v = acc[mi][ni][jr];
            v = 0.5f * v * (1.0f + erff(v * 0.70710678118654752f));
            int col = n0 + wn + ni * 16 + r15;
            hout[grow * NDIM + col] = f2b(v);
          }
        } else {
          int tok = ids[e * NTOK + m0 + rl];
          float p = prw[e * NTOK + m0 + rl];
#pragma unroll
          for (int ni = 0; ni < 4; ++ni) {
            int col = n0 + wn + ni * 16 + r15;
            atomicAdd(&yout[(size_t)tok * DDIM + col], p * acc[mi][ni][jr]);
          }
        }
      }
    }
  }
}

extern "C" void kernel_launch(void* const* d_in, const int* in_sizes, int n_in,
                              void* d_out, int out_size, void* d_ws, size_t ws_size,
                              hipStream_t stream) {
  const float* x = (const float*)d_in[0];
  const float* gw = (const float*)d_in[1];
  const float* w1 = (const float*)d_in[2];
  const float* w2 = (const float*)d_in[3];
  float* out = (float*)d_out;
  char* w = (char*)d_ws;
  if (ws_size < WS_NEED) return;  // insufficient workspace -> loud failure

  int* cnt = (int*)(w + WS_CNT);
  float* psum = (float*)(w + WS_PSUM);
  int* ids = (int*)(w + WS_IDS);
  float* prw = (float*)(w + WS_PRW);
  u16* w1t = (u16*)(w + WS_W1T);
  u16* w2t = (u16*)(w + WS_W2T);
  u16* hbuf = (u16*)(w + WS_H);
  u16* xb = (u16*)(w + WS_XB);

  (void)hipMemsetAsync(w, 0, 96, stream);
  // prep: router (emits xb) + w1 transpose + output zeroing
  prep_kernel<<<4736, 256, 0, stream>>>(x, gw, out, cnt, psum, ids, prw, xb, w1, w1t);
  // GEMM1 + co-scheduled w2 transpose (1:2 interleave); aux written by gid 0
  moe_gemm_kernel<0><<<12288, 256, 0, stream>>>(
      xb, w1t, hbuf, nullptr, cnt, psum, ids, prw, out, w2, w2t);
  // GEMM2 with split-K=2 (atomic partial sums; better block packing / tail)
  moe_gemm_kernel<1><<<8192, 256, 0, stream>>>(
      hbuf, w2t, nullptr, out + OFF_OUT, cnt, psum, ids, prw, out, nullptr, nullptr);
}

// Round 21
// 299.276 us; speedup vs baseline: 1.1648x; 1.1648x over previous
//
#include <hip/hip_runtime.h>
#include <hip/hip_bf16.h>
#include <cstdint>

typedef unsigned short u16;
typedef unsigned int u32;
typedef short s16x8 __attribute__((ext_vector_type(8)));
typedef float f32x4 __attribute__((ext_vector_type(4)));

// Problem constants (B=4, T=2048, D=1024, E=8, H=2048, K=2)
constexpr int NTOK = 8192;
constexpr int DDIM = 1024;
constexpr int NEXP = 8;
constexpr int HDIM = 2048;
constexpr int NPAIR = NTOK * 2;   // 16384

// d_out layout (floats), concatenated tuple
constexpr size_t OFF_OUT   = 0;
constexpr size_t OFF_AUX   = 8388608;
constexpr size_t OFF_PROBS = 8388609;
constexpr size_t OFF_TIDX  = 8454145;
constexpr size_t OFF_TPR   = 8470529;

// workspace layout (bytes)
constexpr size_t WS_CNT  = 0;          // 8 int
constexpr size_t WS_PSUM = 32;         // 8 float
constexpr size_t WS_IDS  = 1024;       // 8*8192 int   -> ends 263168
constexpr size_t WS_PRW  = 263168;     // 8*8192 float -> ends 525312
constexpr size_t WS_W1T  = 17302528;   // 8*2048*1024 bf16 (transposed [E][H][D])
constexpr size_t WS_W2T  = 50856960;   // 8*1024*2048 bf16 (transposed [E][D][H])
constexpr size_t WS_H    = 84411392;   // 16384*2048 bf16
constexpr size_t WS_XB   = 151520256;  // 8192*1024 bf16 (x converted, token order)
constexpr size_t WS_NEED = 168297472;

__device__ __forceinline__ u16 f2b(float f) {
  u32 u = __float_as_uint(f);
  u32 r = (u + 0x7fffu + ((u >> 16) & 1u)) >> 16;
  return (u16)r;
}

typedef const uint32_t __attribute__((address_space(1)))* gptr_t;
typedef uint32_t __attribute__((address_space(3)))* lptr_t;

__device__ __forceinline__ void gload16(const void* gp, void* lp) {
  __builtin_amdgcn_global_load_lds((gptr_t)gp, (lptr_t)(uintptr_t)lp, 16, 0, 0);
}

// ======== PREP: router (0..127) + w1 transpose (128..4223) + out-zeroing (4224..4735) ========
// w2's transpose moved into the GEMM1 dispatch (only GEMM2 needs w2t).
__global__ __launch_bounds__(256) void prep_kernel(
    const float* __restrict__ x, const float* __restrict__ gw,
    float* __restrict__ outbuf,
    int* __restrict__ cnt, float* __restrict__ psum,
    int* __restrict__ ids, float* __restrict__ prw, u16* __restrict__ xb,
    const float* __restrict__ w1, u16* __restrict__ w1t) {
  __shared__ float smem[DDIM * NEXP];  // 32 KB: router gate staging / tconv tile
  __shared__ int lcnt[NEXP];
  __shared__ float psl[NEXP];
  __shared__ int gbl[NEXP];

  const int bid = blockIdx.x;
  const int tid = threadIdx.x;

  if (bid >= 4224) {
    // ---------------- out-zeroing role (32 MB over 512 blocks) ----------------
    float4 z = {0.f, 0.f, 0.f, 0.f};
    float4* dst = (float4*)(outbuf + OFF_OUT) + (size_t)(bid - 4224) * 4096 + tid;
#pragma unroll
    for (int i = 0; i < 16; ++i) dst[i * 256] = z;
    return;
  }

  if (bid >= 128) {
    // ---------------- w1 tconv role: [E][1024][2048] -> [E][2048][1024] ----------------
    int id = bid - 128;
    int e = id >> 9, r = id & 511;
    int c0 = (r & 31) * 64, r0 = (r >> 5) * 64;

    float (*tile)[65] = (float(*)[65])smem;
    int tx = tid & 15, ty = tid >> 4;
    const float* src = w1 + (size_t)e * DDIM * HDIM;
#pragma unroll
    for (int i = 0; i < 4; ++i) {
      int rr = ty + i * 16;
      float4 v = *(const float4*)(src + (size_t)(r0 + rr) * HDIM + c0 + tx * 4);
      tile[rr][tx * 4 + 0] = v.x; tile[rr][tx * 4 + 1] = v.y;
      tile[rr][tx * 4 + 2] = v.z; tile[rr][tx * 4 + 3] = v.w;
    }
    __syncthreads();
    u16* dst = w1t + (size_t)e * DDIM * HDIM;
#pragma unroll
    for (int i = 0; i < 4; ++i) {
      int c = ty + i * 16;
      ushort4 o;
      o.x = f2b(tile[tx * 4 + 0][c]); o.y = f2b(tile[tx * 4 + 1][c]);
      o.z = f2b(tile[tx * 4 + 2][c]); o.w = f2b(tile[tx * 4 + 3][c]);
      *(ushort4*)(dst + (size_t)(c0 + c) * DDIM + r0 + tx * 4) = o;
    }
    return;
  }

  // ---------------- router role (also emits xb = bf16(x)) ----------------
#pragma unroll
  for (int k = 0; k < 8; ++k)
    ((float4*)smem)[tid + k * 256] = ((const float4*)gw)[tid + k * 256];
  if (tid < NEXP) { lcnt[tid] = 0; psl[tid] = 0.f; }
  __syncthreads();

  const int tloc = tid >> 2, part = tid & 3;
  const int t = bid * 64 + tloc;
  double acc[NEXP];
#pragma unroll
  for (int e = 0; e < NEXP; ++e) acc[e] = 0.0;

  const float* xrow = x + (size_t)t * DDIM + part * 256;
  u16* xbrow = xb + (size_t)t * DDIM + part * 256;
  for (int i = 0; i < 64; ++i) {
    float4 v = ((const float4*)xrow)[i];
    ushort4 o;
    o.x = f2b(v.x); o.y = f2b(v.y); o.z = f2b(v.z); o.w = f2b(v.w);
    ((ushort4*)xbrow)[i] = o;
    const float* g = &smem[(part * 256 + i * 4) * NEXP];
#pragma unroll
    for (int j = 0; j < 4; ++j) {
      double xs = (double)((const float*)&v)[j];
#pragma unroll
      for (int e = 0; e < NEXP; ++e) acc[e] += xs * (double)g[j * NEXP + e];
    }
  }
#pragma unroll
  for (int e = 0; e < NEXP; ++e) {
    acc[e] += __shfl_xor(acc[e], 1);
    acc[e] += __shfl_xor(acc[e], 2);
  }

  int e0 = 0, e1 = 0, lp0 = 0, lp1 = 0;
  float tp0 = 0.f, tp1 = 0.f;
  if (part == 0) {
    float l[NEXP];
#pragma unroll
    for (int e = 0; e < NEXP; ++e) l[e] = (float)acc[e];
    float m = l[0];
#pragma unroll
    for (int e = 1; e < NEXP; ++e) m = fmaxf(m, l[e]);
    float p[NEXP], s = 0.f;
#pragma unroll
    for (int e = 0; e < NEXP; ++e) { p[e] = expf(l[e] - m); s += p[e]; }
    float inv = 1.0f / s;
#pragma unroll
    for (int e = 0; e < NEXP; ++e) {
      p[e] *= inv;
      outbuf[OFF_PROBS + (size_t)t * NEXP + e] = p[e];
      atomicAdd(&psl[e], p[e]);
    }
#pragma unroll
    for (int e = 1; e < NEXP; ++e) if (p[e] > p[e0]) e0 = e;
    e1 = -1;
#pragma unroll
    for (int e = 0; e < NEXP; ++e)
      if (e != e0 && (e1 < 0 || p[e] > p[e1])) e1 = e;
    float ps = p[e0] + p[e1];
    tp0 = p[e0] / ps;
    tp1 = p[e1] / ps;
    outbuf[OFF_TIDX + t * 2 + 0] = (float)e0;
    outbuf[OFF_TIDX + t * 2 + 1] = (float)e1;
    outbuf[OFF_TPR + t * 2 + 0] = tp0;
    outbuf[OFF_TPR + t * 2 + 1] = tp1;
    lp0 = atomicAdd(&lcnt[e0], 1);
    lp1 = atomicAdd(&lcnt[e1], 1);
  }
  __syncthreads();
  if (tid < NEXP) {
    gbl[tid] = atomicAdd(&cnt[tid], lcnt[tid]);
    atomicAdd(&psum[tid], psl[tid]);
  }
  __syncthreads();
  if (part == 0) {
    int pos0 = gbl[e0] + lp0;
    int pos1 = gbl[e1] + lp1;
    ids[e0 * NTOK + pos0] = t;
    ids[e1 * NTOK + pos1] = t;
    prw[e0 * NTOK + pos0] = tp0;
    prw[e1 * NTOK + pos1] = tp1;
  }
}

// -------- grouped GEMM: 128x128, BK=32, 3-ring one-barrier, supertile (R13-proven) --------
// MODE 0 grid = 12288: every 3rd block (r3==2) transposes one w2 tile (w2t needed only
// by GEMM2 -> hides under GEMM1's compute); GEMM blocks use gid = g3*2+r3 (0..8191).
// MODE 1 grid = 4096 plain.
// Ring: vmcnt(4) -> barrier -> STAGE(kt+2) -> compute(kt). XCD-affinity e = gid&7.
template <int MODE>
__global__ __launch_bounds__(256, 3) void moe_gemm_kernel(
    const u16* __restrict__ Asrc, const u16* __restrict__ Bt,
    u16* __restrict__ hout, float* __restrict__ yout,
    const int* __restrict__ cnt, const float* __restrict__ psum,
    const int* __restrict__ ids, const float* __restrict__ prw,
    float* __restrict__ outbuf,
    const float* __restrict__ w2, u16* __restrict__ w2t) {
  constexpr int KDIM = (MODE == 0) ? 1024 : 2048;
  constexpr int NDIM = (MODE == 0) ? 2048 : 1024;
  constexpr int NT = KDIM / 32;
  constexpr int NB = NDIM / 128;   // n-blocks per expert
  constexpr int MGRP = 4;          // m-blocks per L2 supertile group
  constexpr int QPG = MGRP * NB;   // q's per group

  __shared__ u16 Al[3][128 * 32];  // 24 KB
  __shared__ u16 Bl[3][128 * 32];  // 24 KB

  const int wgid = blockIdx.x;
  const int tid = threadIdx.x;
  int gid;
  if (MODE == 0) {
    int g3 = wgid / 3, r3 = wgid - g3 * 3;
    if (r3 == 2) {
      // ---------------- w2 tconv role: [E][2048][1024] -> [E][1024][2048] ----------------
      int e = g3 >> 9, r = g3 & 511;
      int c0 = (r & 15) * 64, r0 = (r >> 4) * 64;
      float (*tile)[65] = (float(*)[65])Al;  // overlay on GEMM LDS (16.6 KB < 48 KB)
      int tx = tid & 15, ty = tid >> 4;
      const float* src = w2 + (size_t)e * HDIM * DDIM;
#pragma unroll
      for (int i = 0; i < 4; ++i) {
        int rr = ty + i * 16;
        float4 v = *(const float4*)(src + (size_t)(r0 + rr) * DDIM + c0 + tx * 4);
        tile[rr][tx * 4 + 0] = v.x; tile[rr][tx * 4 + 1] = v.y;
        tile[rr][tx * 4 + 2] = v.z; tile[rr][tx * 4 + 3] = v.w;
      }
      __syncthreads();
      u16* dst = w2t + (size_t)e * HDIM * DDIM;
#pragma unroll
      for (int i = 0; i < 4; ++i) {
        int c = ty + i * 16;
        ushort4 o;
        o.x = f2b(tile[tx * 4 + 0][c]); o.y = f2b(tile[tx * 4 + 1][c]);
        o.z = f2b(tile[tx * 4 + 2][c]); o.w = f2b(tile[tx * 4 + 3][c]);
        *(ushort4*)(dst + (size_t)(c0 + c) * HDIM + r0 + tx * 4) = o;
      }
      return;
    }
    gid = g3 * 2 + r3;
  } else {
    gid = wgid;
  }

  const int e = gid & 7;           // expert -> XCD lane
  const int q = gid >> 3;
  const int mg = q / QPG;
  const int r = q % QPG;
  const int m0 = (mg * MGRP + (r % MGRP)) * 128;
  const int n0 = (r / MGRP) * 128;

  int cn[NEXP];
#pragma unroll
  for (int i = 0; i < NEXP; ++i) cn[i] = cnt[i];
  const int cnte = cn[e];

  if (MODE == 0 && gid == 0 && tid == 0) {
    float aux = 0.f;
#pragma unroll
    for (int i = 0; i < NEXP; ++i) aux += (float)cn[i] * psum[i];
    outbuf[OFF_AUX] = aux * (float)NEXP / ((float)NTOK * (float)NTOK);
  }

  if (m0 >= cnte) return;
  int gbase = 0;
#pragma unroll
  for (int i = 0; i < NEXP; ++i) if (i < e) gbase += cn[i];

  const int lane = tid & 63, wid = tid >> 6;
  const int wm = (wid >> 1) * 64, wn = (wid & 1) * 64;
  const int r15 = lane & 15, l4 = lane >> 4;

  // staging precompute: per qq, LDS slot j=qq*256+tid -> row=j>>2, chunk cp=j&3,
  // holds global chunk c = cp ^ ((row>>1)&3)  (both-sides XOR swizzle)
  const char* aptr[2];
  const char* bptr[2];
#pragma unroll
  for (int qq = 0; qq < 2; ++qq) {
    int j = qq * 256 + tid;
    int row = j >> 2;
    int c = (j & 3) ^ ((row >> 1) & 3);
    size_t rowoff;
    if (MODE == 0) {
      int mm = m0 + row;
      if (mm > cnte - 1) mm = cnte - 1;
      int tok = ids[e * NTOK + mm];          // in-GEMM gather
      rowoff = (size_t)tok * KDIM;
    } else {
      int gr = gbase + m0 + row;
      if (gr > NPAIR - 1) gr = NPAIR - 1;
      rowoff = (size_t)gr * KDIM;
    }
    aptr[qq] = (const char*)Asrc + (rowoff + (size_t)c * 8) * 2;
    size_t nrow = (size_t)e * NDIM + n0 + row;
    bptr[qq] = (const char*)Bt + (nrow * KDIM + (size_t)c * 8) * 2;
  }

  f32x4 acc[4][4];
#pragma unroll
  for (int i = 0; i < 4; ++i)
#pragma unroll
    for (int jn = 0; jn < 4; ++jn) acc[i][jn] = (f32x4){0.f, 0.f, 0.f, 0.f};

#define STAGE(b_, kt_)                                                         \
  do {                                                                         \
    const size_t kofs_ = (size_t)(kt_) * 64;  /* bytes: 32 bf16 */             \
    _Pragma("unroll") for (int qq = 0; qq < 2; ++qq) {                         \
      gload16(aptr[qq] + kofs_, (void*)&Al[b_][(size_t)(qq * 256 + tid) * 8]); \
      gload16(bptr[qq] + kofs_, (void*)&Bl[b_][(size_t)(qq * 256 + tid) * 8]); \
    }                                                                          \
  } while (0)

  auto compute = [&](int b) {
    const s16x8* Av = (const s16x8*)Al[b];
    const s16x8* Bv = (const s16x8*)Bl[b];
    s16x8 af[4], bfr[4];
#pragma unroll
    for (int mi = 0; mi < 4; ++mi) {
      int row = wm + mi * 16 + r15;
      af[mi] = Av[row * 4 + (l4 ^ ((row >> 1) & 3))];
    }
#pragma unroll
    for (int ni = 0; ni < 4; ++ni) {
      int row = wn + ni * 16 + r15;
      bfr[ni] = Bv[row * 4 + (l4 ^ ((row >> 1) & 3))];
    }
#pragma unroll
    for (int mi = 0; mi < 4; ++mi)
#pragma unroll
      for (int ni = 0; ni < 4; ++ni)
        acc[mi][ni] = __builtin_amdgcn_mfma_f32_16x16x32_bf16(
            af[mi], bfr[ni], acc[mi][ni], 0, 0, 0);
  };

  // prologue: tiles 0,1 staged into bufs 0,1 (8 loads/thread outstanding)
  STAGE(0, 0);
  STAGE(1, 1);

  int b0 = 0;
  for (int kt = 0; kt < NT; ++kt) {
    if (kt < NT - 1)
      asm volatile("s_waitcnt vmcnt(4)" ::: "memory");  // tile kt landed, kt+1 in flight
    else
      asm volatile("s_waitcnt vmcnt(0)" ::: "memory");  // last tile: drain
    __builtin_amdgcn_s_barrier();  // all waves: tile kt ready AND compute(kt-1) done
    asm volatile("" ::: "memory");
    if (kt + 2 < NT) {
      int bs = b0 + 2; if (bs >= 3) bs -= 3;
      STAGE(bs, kt + 2);  // into buffer freed by compute(kt-1)
    }
    compute(b0);
    if (++b0 == 3) b0 = 0;
  }
#undef STAGE

  // epilogue: C/D layout col = lane&15, row = (lane>>4)*4 + j
#pragma unroll
  for (int mi = 0; mi < 4; ++mi) {
#pragma unroll
    for (int jr = 0; jr < 4; ++jr) {
      int rl = wm + mi * 16 + l4 * 4 + jr;
      if (m0 + rl < cnte) {
        if (MODE == 0) {
          size_t grow = (size_t)(gbase + m0 + rl);
#pragma unroll
          for (int ni = 0; ni < 4; ++ni) {
            float v = acc[mi][ni][jr];
            v = 0.5f * v * (1.0f + erff(v * 0.70710678118654752f));
            int col = n0 + wn + ni * 16 + r15;
            hout[grow * NDIM + col] = f2b(v);
          }
        } else {
          int tok = ids[e * NTOK + m0 + rl];
          float p = prw[e * NTOK + m0 + rl];
#pragma unroll
          for (int ni = 0; ni < 4; ++ni) {
            int col = n0 + wn + ni * 16 + r15;
            atomicAdd(&yout[(size_t)tok * DDIM + col], p * acc[mi][ni][jr]);
          }
        }
      }
    }
  }
}

extern "C" void kernel_launch(void* const* d_in, const int* in_sizes, int n_in,
                              void* d_out, int out_size, void* d_ws, size_t ws_size,
                              hipStream_t stream) {
  const float* x = (const float*)d_in[0];
  const float* gw = (const float*)d_in[1];
  const float* w1 = (const float*)d_in[2];
  const float* w2 = (const float*)d_in[3];
  float* out = (float*)d_out;
  char* w = (char*)d_ws;
  if (ws_size < WS_NEED) return;  // insufficient workspace -> loud failure

  int* cnt = (int*)(w + WS_CNT);
  float* psum = (float*)(w + WS_PSUM);
  int* ids = (int*)(w + WS_IDS);
  float* prw = (float*)(w + WS_PRW);
  u16* w1t = (u16*)(w + WS_W1T);
  u16* w2t = (u16*)(w + WS_W2T);
  u16* hbuf = (u16*)(w + WS_H);
  u16* xb = (u16*)(w + WS_XB);

  (void)hipMemsetAsync(w, 0, 96, stream);
  // prep: router (emits xb) + w1 transpose + output zeroing
  prep_kernel<<<4736, 256, 0, stream>>>(x, gw, out, cnt, psum, ids, prw, xb, w1, w1t);
  // GEMM1 + co-scheduled w2 transpose (1:2 interleave); aux written by gid 0
  moe_gemm_kernel<0><<<12288, 256, 0, stream>>>(
      xb, w1t, hbuf, nullptr, cnt, psum, ids, prw, out, w2, w2t);
  moe_gemm_kernel<1><<<NEXP * 64 * (DDIM / 128), 256, 0, stream>>>(
      hbuf, w2t, nullptr, out + OFF_OUT, cnt, psum, ids, prw, out, nullptr, nullptr);
}